// Round 4
// baseline (275.573 us; speedup 1.0000x reference)
//
#include <hip/hip_runtime.h>
#include <hip/hip_bf16.h>

// N_NODES=100000, N_EDGES=800000, FEAT=64, NNZ=1600000
// Inputs: 0 edge_list [N,64] f32 | 1 X1 [E,2] i32 | 2 W [64,64] f32 | 3 b [64] f32
//         4 prelu_w [1] f32 | 5 b1_rows [NNZ] i32 | 6 b1_cols [NNZ] i32 | 7 b1_vals [NNZ] f32
// Output: [N,64] f32
//
// out = PReLU( (B1 @ Xe) @ W^T + (B1 @ 1) b^T ),  Xe[c] = (n[u_c]-n[v_c])^2
//
// Round-4: gather MLP. entries are 8B {col, val}; gather_agg unrolls by 4 with
// batched independent loads (8 node-row gathers in flight per wave) and a
// cndmask'd tail (no entry memset needed).

#define FEAT 64
#define CAP  64   // Poisson(16) row degree; P(deg>64) ~ 1e-15 per row, guarded

typedef __attribute__((ext_vector_type(8))) short bf16x8;
typedef __attribute__((ext_vector_type(4))) float f32x4;

__device__ inline short f2bf(float x) {
  union { __hip_bfloat16 h; short s; } u;
  u.h = __float2bfloat16(x);   // RNE
  return u.s;
}

// ---------------------------------------------------------------------------
// Kernel 1: bucket nnz by row. entries[r*CAP+k] = {col, val_bits} (8B).
// ---------------------------------------------------------------------------
__global__ __launch_bounds__(256) void fill_entries_kernel(
    const int*   __restrict__ rows,     // [NNZ]
    const int*   __restrict__ cols,     // [NNZ]
    const float* __restrict__ vals,     // [NNZ]
    int*         __restrict__ cnt,      // [N] pre-zeroed
    int2*        __restrict__ entries,  // [N*CAP]
    int nnz) {
  const int i = blockIdx.x * blockDim.x + threadIdx.x;
  if (i >= nnz) return;
  const int r = rows[i];
  const int c = cols[i];
  const float v = vals[i];
  const int k = atomicAdd(&cnt[r], 1);
  if (k < CAP) {
    int2 e;
    e.x = c;
    e.y = __float_as_int(v);
    entries[(size_t)r * CAP + k] = e;
  }
}

// ---------------------------------------------------------------------------
// Kernel 2: per-row gather-aggregate, 4x unrolled with batched loads.
// One wave per row; lane j = feature j.
//   agg[r,j] = sum_k val_k * (nodes[u_k,j] - nodes[w_k,j])^2 ; rowsum[r] = sum val
// ---------------------------------------------------------------------------
__global__ __launch_bounds__(256) void gather_agg_kernel(
    const float* __restrict__ nodes,    // [N,64]
    const int*   __restrict__ X1,       // [E,2]
    const int*   __restrict__ cnt,      // [N]
    const int2*  __restrict__ entries,  // [N*CAP]
    float*       __restrict__ agg,      // [N,64]
    float*       __restrict__ rowsum,   // [N]
    int N) {
  const int lane = threadIdx.x & 63;
  const int r = blockIdx.x * (blockDim.x >> 6) + (threadIdx.x >> 6);
  if (r >= N) return;

  int deg = cnt[r];
  if (deg > CAP) deg = CAP;
  const int2* base = &entries[(size_t)r * CAP];
  const int2* X1v  = reinterpret_cast<const int2*>(X1);

  float acc = 0.f, rsum = 0.f;

  for (int k = 0; k < deg; k += 4) {
    // Batch-load 4 entries (wave-uniform addresses; stays within CAP since
    // k <= deg-1 <= 63 and groups are 4-aligned -> k+3 <= 63).
    const int2 e0 = base[k + 0];
    const int2 e1 = base[k + 1];
    const int2 e2 = base[k + 2];
    const int2 e3 = base[k + 3];

    // Mask the (at most one) partial tail group. Garbage entries are never
    // dereferenced: index forced to 0, weight to 0.
    const bool m1 = (k + 1 < deg), m2 = (k + 2 < deg), m3 = (k + 3 < deg);
    const int   c0 = e0.x;
    const int   c1 = m1 ? e1.x : 0;
    const int   c2 = m2 ? e2.x : 0;
    const int   c3 = m3 ? e3.x : 0;
    const float v0 = __int_as_float(e0.y);
    const float v1 = m1 ? __int_as_float(e1.y) : 0.f;
    const float v2 = m2 ? __int_as_float(e2.y) : 0.f;
    const float v3 = m3 ? __int_as_float(e3.y) : 0.f;

    // 4 independent X1 lookups (wave-uniform, L2-resident 6.4 MB table).
    const int2 uv0 = X1v[c0];
    const int2 uv1 = X1v[c1];
    const int2 uv2 = X1v[c2];
    const int2 uv3 = X1v[c3];

    // 8 independent node-row gathers.
    const float a0 = nodes[(size_t)uv0.x * FEAT + lane];
    const float b0 = nodes[(size_t)uv0.y * FEAT + lane];
    const float a1 = nodes[(size_t)uv1.x * FEAT + lane];
    const float b1 = nodes[(size_t)uv1.y * FEAT + lane];
    const float a2 = nodes[(size_t)uv2.x * FEAT + lane];
    const float b2 = nodes[(size_t)uv2.y * FEAT + lane];
    const float a3 = nodes[(size_t)uv3.x * FEAT + lane];
    const float b3 = nodes[(size_t)uv3.y * FEAT + lane];

    rsum += (v0 + v1) + (v2 + v3);
    const float d0 = a0 - b0;
    const float d1 = a1 - b1;
    const float d2 = a2 - b2;
    const float d3 = a3 - b3;
    acc = fmaf(v0 * d0, d0, acc);
    acc = fmaf(v1 * d1, d1, acc);
    acc = fmaf(v2 * d2, d2, acc);
    acc = fmaf(v3 * d3, d3, acc);
  }

  agg[(size_t)r * FEAT + lane] = acc;
  if (lane == 0) rowsum[r] = rsum;
}

// ---------------------------------------------------------------------------
// Kernel 3: out = PReLU( agg @ W^T + rowsum * b )  via mfma_f32_16x16x32_bf16.
// Fragment layouts (gfx950, m89/m91-verified):
//   A[i][k]: i = lane&15, k = (lane>>4)*8 + e   (e = 0..7)
//   B[k][j]: j = lane&15, k = (lane>>4)*8 + e
//   D[i][j]: j = lane&15, i = (lane>>4)*4 + reg (reg = 0..3)
// ---------------------------------------------------------------------------
__global__ __launch_bounds__(256) void final_gemm_kernel(
    const float* __restrict__ agg,     // [N,64]
    const float* __restrict__ rowsum,  // [N]
    const float* __restrict__ W,       // [64,64]
    const float* __restrict__ bias,    // [64]
    const float* __restrict__ pw,      // [1]
    float*       __restrict__ out,     // [N,64]
    int nrows) {
  const int lane = threadIdx.x & 63;
  const int gw = blockIdx.x * (blockDim.x >> 6) + (threadIdx.x >> 6);
  const int nw = gridDim.x * (blockDim.x >> 6);

  const int lrow = lane & 15;
  const int kgrp = lane >> 4;
  const int k0   = kgrp * 8;

  bf16x8 bfrag[4][2];
#pragma unroll
  for (int jt = 0; jt < 4; ++jt) {
#pragma unroll
    for (int ks = 0; ks < 2; ++ks) {
      const float* wr = &W[(jt * 16 + lrow) * FEAT + ks * 32 + k0];
      bf16x8 t;
#pragma unroll
      for (int e = 0; e < 8; ++e) t[e] = f2bf(wr[e]);
      bfrag[jt][ks] = t;
    }
  }
  const float slope = pw[0];
  float bj[4];
#pragma unroll
  for (int jt = 0; jt < 4; ++jt) bj[jt] = bias[jt * 16 + lrow];

  const int ntiles = nrows >> 4;   // 100000 / 16 = 6250
  for (int t = gw; t < ntiles; t += nw) {
    const int rowbase = t * 16;

    bf16x8 afrag[2];
#pragma unroll
    for (int ks = 0; ks < 2; ++ks) {
      const float* ar = &agg[(size_t)(rowbase + lrow) * FEAT + ks * 32 + k0];
      f32x4 a0 = *reinterpret_cast<const f32x4*>(ar);
      f32x4 a1 = *reinterpret_cast<const f32x4*>(ar + 4);
      bf16x8 ta;
#pragma unroll
      for (int e = 0; e < 4; ++e) { ta[e] = f2bf(a0[e]); ta[4 + e] = f2bf(a1[e]); }
      afrag[ks] = ta;
    }

    float rs[4];
#pragma unroll
    for (int reg = 0; reg < 4; ++reg) rs[reg] = rowsum[rowbase + kgrp * 4 + reg];

#pragma unroll
    for (int jt = 0; jt < 4; ++jt) {
      f32x4 acc = {0.f, 0.f, 0.f, 0.f};
      acc = __builtin_amdgcn_mfma_f32_16x16x32_bf16(afrag[0], bfrag[jt][0], acc, 0, 0, 0);
      acc = __builtin_amdgcn_mfma_f32_16x16x32_bf16(afrag[1], bfrag[jt][1], acc, 0, 0, 0);
#pragma unroll
      for (int reg = 0; reg < 4; ++reg) {
        float y = acc[reg] + rs[reg] * bj[jt];
        y = y >= 0.f ? y : slope * y;
        out[(size_t)(rowbase + kgrp * 4 + reg) * FEAT + jt * 16 + lrow] = y;
      }
    }
  }
}

// ---------------------------------------------------------------------------
// Fallback (ws too small): atomic scatter path (round-2).
// ---------------------------------------------------------------------------
__global__ __launch_bounds__(256) void scatter_xe_kernel(
    const float* __restrict__ nodes,
    const int*   __restrict__ X1,
    const int*   __restrict__ rows,
    const int*   __restrict__ cols,
    const float* __restrict__ vals,
    float*       __restrict__ agg,
    float*       __restrict__ rowsum,
    int nnz) {
  const int lane = threadIdx.x & 63;
  const int gw = blockIdx.x * (blockDim.x >> 6) + (threadIdx.x >> 6);
  const int nw = gridDim.x * (blockDim.x >> 6);
  for (int i = gw; i < nnz; i += nw) {
    const int r = rows[i];
    const int c = cols[i];
    const float v = vals[i];
    const int u = X1[2 * c + 0];
    const int w = X1[2 * c + 1];
    const float a = nodes[(size_t)u * FEAT + lane];
    const float b = nodes[(size_t)w * FEAT + lane];
    const float d = a - b;
    atomicAdd(&agg[(size_t)r * FEAT + lane], v * d * d);
    if (lane == 0) atomicAdd(&rowsum[r], v);
  }
}

extern "C" void kernel_launch(void* const* d_in, const int* in_sizes, int n_in,
                              void* d_out, int out_size, void* d_ws, size_t ws_size,
                              hipStream_t stream) {
  const float* nodes  = (const float*)d_in[0];
  const int*   X1     = (const int*)d_in[1];
  const float* W      = (const float*)d_in[2];
  const float* bias   = (const float*)d_in[3];
  const float* preluw = (const float*)d_in[4];
  const int*   rows   = (const int*)d_in[5];
  const int*   cols   = (const int*)d_in[6];
  const float* vals   = (const float*)d_in[7];
  float* out = (float*)d_out;

  const int N   = in_sizes[0] / FEAT;  // 100000
  const int nnz = in_sizes[5];         // 1600000

  // ws layout: cnt [N] i32 | rowsum [N] f32 | agg [N*64] f32 | entries [N*CAP] int2
  int*   cnt     = (int*)d_ws;
  float* rowsum  = (float*)(cnt + N);
  float* agg     = (float*)(rowsum + N);
  int2*  entries = (int2*)(agg + (size_t)N * FEAT);
  const size_t need = (size_t)N * 8 + (size_t)N * FEAT * 4 + (size_t)N * CAP * 8;

  if (ws_size >= need) {
    hipMemsetAsync(cnt, 0, (size_t)N * sizeof(int), stream);
    fill_entries_kernel<<<(nnz + 255) / 256, 256, 0, stream>>>(
        rows, cols, vals, cnt, entries, nnz);
    gather_agg_kernel<<<(N + 3) / 4, 256, 0, stream>>>(
        nodes, X1, cnt, entries, agg, rowsum, N);
    final_gemm_kernel<<<1563, 256, 0, stream>>>(agg, rowsum, W, bias, preluw,
                                                out, N);
  } else {
    float* agg2    = (float*)d_ws;
    float* rowsum2 = agg2 + (size_t)N * FEAT;
    hipMemsetAsync(d_ws, 0, ((size_t)N * FEAT + N) * sizeof(float), stream);
    scatter_xe_kernel<<<4096, 256, 0, stream>>>(nodes, X1, rows, cols, vals,
                                                agg2, rowsum2, nnz);
    final_gemm_kernel<<<1563, 256, 0, stream>>>(agg2, rowsum2, W, bias, preluw,
                                                out, N);
  }
}

// Round 5
// 220.254 us; speedup vs baseline: 1.2512x; 1.2512x over previous
//
#include <hip/hip_runtime.h>
#include <hip/hip_bf16.h>

// N_NODES=100000, N_EDGES=800000, FEAT=64, NNZ=1600000
// Inputs: 0 edge_list [N,64] f32 | 1 X1 [E,2] i32 | 2 W [64,64] f32 | 3 b [64] f32
//         4 prelu_w [1] f32 | 5 b1_rows [NNZ] i32 | 6 b1_cols [NNZ] i32 | 7 b1_vals [NNZ] f32
// Output: [N,64] f32
//
// out = PReLU( (B1 @ Xe) @ W^T + (B1 @ 1) b^T ),  Xe[c] = (n[u_c]-n[v_c])^2
//
// Round-5: 16B entries {u,w,val} resolved in fill (round-3) + 4x batched
// gather unroll (round-4). Entry->gather chain is 2 levels with 8 independent
// node-row gathers in flight per wave.

#define FEAT 64
#define CAP  64   // Poisson(16) row degree; P(deg>64) ~ 1e-15 per row, guarded

typedef __attribute__((ext_vector_type(8))) short bf16x8;
typedef __attribute__((ext_vector_type(4))) float f32x4;

__device__ inline short f2bf(float x) {
  union { __hip_bfloat16 h; short s; } u;
  u.h = __float2bfloat16(x);   // RNE
  return u.s;
}

// ---------------------------------------------------------------------------
// Kernel 1: bucket nnz by row, resolving X1 once: entries[r*CAP+k]={u,w,val}.
// ---------------------------------------------------------------------------
__global__ __launch_bounds__(256) void fill_entries_kernel(
    const int*   __restrict__ rows,     // [NNZ]
    const int*   __restrict__ cols,     // [NNZ]
    const float* __restrict__ vals,     // [NNZ]
    const int*   __restrict__ X1,       // [E,2]
    int*         __restrict__ cnt,      // [N] pre-zeroed
    int4*        __restrict__ entries,  // [N*CAP]
    int nnz) {
  const int i = blockIdx.x * blockDim.x + threadIdx.x;
  if (i >= nnz) return;
  const int r = rows[i];
  const int c = cols[i];
  const float v = vals[i];
  const int2 uv = *reinterpret_cast<const int2*>(&X1[2 * c]);
  const int k = atomicAdd(&cnt[r], 1);
  if (k < CAP) {
    int4 e;
    e.x = uv.x; e.y = uv.y; e.z = __float_as_int(v); e.w = 0;
    entries[(size_t)r * CAP + k] = e;
  }
}

// ---------------------------------------------------------------------------
// Kernel 2: per-row gather-aggregate, 4x unrolled, 8 gathers in flight.
// One wave per row; lane j = feature j.
//   agg[r,j] = sum_k val_k * (nodes[u_k,j] - nodes[w_k,j])^2 ; rowsum[r]=sum val
// ---------------------------------------------------------------------------
__global__ __launch_bounds__(256) void gather_agg_kernel(
    const float* __restrict__ nodes,    // [N,64]
    const int*   __restrict__ cnt,      // [N]
    const int4*  __restrict__ entries,  // [N*CAP]
    float*       __restrict__ agg,      // [N,64]
    float*       __restrict__ rowsum,   // [N]
    int N) {
  const int lane = threadIdx.x & 63;
  const int r = blockIdx.x * (blockDim.x >> 6) + (threadIdx.x >> 6);
  if (r >= N) return;

  int deg = cnt[r];
  if (deg > CAP) deg = CAP;
  const int4* base = &entries[(size_t)r * CAP];

  float acc = 0.f, rsum = 0.f;

  for (int k = 0; k < deg; k += 4) {
    // 4 wave-uniform entry loads (within CAP: groups 4-aligned, k+3 <= 63).
    const int4 e0 = base[k + 0];
    const int4 e1 = base[k + 1];
    const int4 e2 = base[k + 2];
    const int4 e3 = base[k + 3];

    // Mask the (at most one) partial tail group: index -> 0, weight -> 0.
    const bool m1 = (k + 1 < deg), m2 = (k + 2 < deg), m3 = (k + 3 < deg);
    const int   u0 = e0.x,            w0 = e0.y;
    const int   u1 = m1 ? e1.x : 0,   w1 = m1 ? e1.y : 0;
    const int   u2 = m2 ? e2.x : 0,   w2 = m2 ? e2.y : 0;
    const int   u3 = m3 ? e3.x : 0,   w3 = m3 ? e3.y : 0;
    const float v0 = __int_as_float(e0.z);
    const float v1 = m1 ? __int_as_float(e1.z) : 0.f;
    const float v2 = m2 ? __int_as_float(e2.z) : 0.f;
    const float v3 = m3 ? __int_as_float(e3.z) : 0.f;

    // 8 independent node-row gathers (256B coalesced each).
    const float a0 = nodes[(size_t)u0 * FEAT + lane];
    const float b0 = nodes[(size_t)w0 * FEAT + lane];
    const float a1 = nodes[(size_t)u1 * FEAT + lane];
    const float b1 = nodes[(size_t)w1 * FEAT + lane];
    const float a2 = nodes[(size_t)u2 * FEAT + lane];
    const float b2 = nodes[(size_t)w2 * FEAT + lane];
    const float a3 = nodes[(size_t)u3 * FEAT + lane];
    const float b3 = nodes[(size_t)w3 * FEAT + lane];

    rsum += (v0 + v1) + (v2 + v3);
    const float d0 = a0 - b0;
    const float d1 = a1 - b1;
    const float d2 = a2 - b2;
    const float d3 = a3 - b3;
    acc = fmaf(v0 * d0, d0, acc);
    acc = fmaf(v1 * d1, d1, acc);
    acc = fmaf(v2 * d2, d2, acc);
    acc = fmaf(v3 * d3, d3, acc);
  }

  agg[(size_t)r * FEAT + lane] = acc;
  if (lane == 0) rowsum[r] = rsum;
}

// ---------------------------------------------------------------------------
// Kernel 3: out = PReLU( agg @ W^T + rowsum * b )  via mfma_f32_16x16x32_bf16.
// Fragment layouts (gfx950, m89/m91-verified):
//   A[i][k]: i = lane&15, k = (lane>>4)*8 + e   (e = 0..7)
//   B[k][j]: j = lane&15, k = (lane>>4)*8 + e
//   D[i][j]: j = lane&15, i = (lane>>4)*4 + reg (reg = 0..3)
// ---------------------------------------------------------------------------
__global__ __launch_bounds__(256) void final_gemm_kernel(
    const float* __restrict__ agg,     // [N,64]
    const float* __restrict__ rowsum,  // [N]
    const float* __restrict__ W,       // [64,64]
    const float* __restrict__ bias,    // [64]
    const float* __restrict__ pw,      // [1]
    float*       __restrict__ out,     // [N,64]
    int nrows) {
  const int lane = threadIdx.x & 63;
  const int gw = blockIdx.x * (blockDim.x >> 6) + (threadIdx.x >> 6);
  const int nw = gridDim.x * (blockDim.x >> 6);

  const int lrow = lane & 15;
  const int kgrp = lane >> 4;
  const int k0   = kgrp * 8;

  bf16x8 bfrag[4][2];
#pragma unroll
  for (int jt = 0; jt < 4; ++jt) {
#pragma unroll
    for (int ks = 0; ks < 2; ++ks) {
      const float* wr = &W[(jt * 16 + lrow) * FEAT + ks * 32 + k0];
      bf16x8 t;
#pragma unroll
      for (int e = 0; e < 8; ++e) t[e] = f2bf(wr[e]);
      bfrag[jt][ks] = t;
    }
  }
  const float slope = pw[0];
  float bj[4];
#pragma unroll
  for (int jt = 0; jt < 4; ++jt) bj[jt] = bias[jt * 16 + lrow];

  const int ntiles = nrows >> 4;   // 100000 / 16 = 6250
  for (int t = gw; t < ntiles; t += nw) {
    const int rowbase = t * 16;

    bf16x8 afrag[2];
#pragma unroll
    for (int ks = 0; ks < 2; ++ks) {
      const float* ar = &agg[(size_t)(rowbase + lrow) * FEAT + ks * 32 + k0];
      f32x4 a0 = *reinterpret_cast<const f32x4*>(ar);
      f32x4 a1 = *reinterpret_cast<const f32x4*>(ar + 4);
      bf16x8 ta;
#pragma unroll
      for (int e = 0; e < 4; ++e) { ta[e] = f2bf(a0[e]); ta[4 + e] = f2bf(a1[e]); }
      afrag[ks] = ta;
    }

    float rs[4];
#pragma unroll
    for (int reg = 0; reg < 4; ++reg) rs[reg] = rowsum[rowbase + kgrp * 4 + reg];

#pragma unroll
    for (int jt = 0; jt < 4; ++jt) {
      f32x4 acc = {0.f, 0.f, 0.f, 0.f};
      acc = __builtin_amdgcn_mfma_f32_16x16x32_bf16(afrag[0], bfrag[jt][0], acc, 0, 0, 0);
      acc = __builtin_amdgcn_mfma_f32_16x16x32_bf16(afrag[1], bfrag[jt][1], acc, 0, 0, 0);
#pragma unroll
      for (int reg = 0; reg < 4; ++reg) {
        float y = acc[reg] + rs[reg] * bj[jt];
        y = y >= 0.f ? y : slope * y;
        out[(size_t)(rowbase + kgrp * 4 + reg) * FEAT + jt * 16 + lrow] = y;
      }
    }
  }
}

// ---------------------------------------------------------------------------
// Fallback (ws too small): atomic scatter path (round-2).
// ---------------------------------------------------------------------------
__global__ __launch_bounds__(256) void scatter_xe_kernel(
    const float* __restrict__ nodes,
    const int*   __restrict__ X1,
    const int*   __restrict__ rows,
    const int*   __restrict__ cols,
    const float* __restrict__ vals,
    float*       __restrict__ agg,
    float*       __restrict__ rowsum,
    int nnz) {
  const int lane = threadIdx.x & 63;
  const int gw = blockIdx.x * (blockDim.x >> 6) + (threadIdx.x >> 6);
  const int nw = gridDim.x * (blockDim.x >> 6);
  for (int i = gw; i < nnz; i += nw) {
    const int r = rows[i];
    const int c = cols[i];
    const float v = vals[i];
    const int u = X1[2 * c + 0];
    const int w = X1[2 * c + 1];
    const float a = nodes[(size_t)u * FEAT + lane];
    const float b = nodes[(size_t)w * FEAT + lane];
    const float d = a - b;
    atomicAdd(&agg[(size_t)r * FEAT + lane], v * d * d);
    if (lane == 0) atomicAdd(&rowsum[r], v);
  }
}

extern "C" void kernel_launch(void* const* d_in, const int* in_sizes, int n_in,
                              void* d_out, int out_size, void* d_ws, size_t ws_size,
                              hipStream_t stream) {
  const float* nodes  = (const float*)d_in[0];
  const int*   X1     = (const int*)d_in[1];
  const float* W      = (const float*)d_in[2];
  const float* bias   = (const float*)d_in[3];
  const float* preluw = (const float*)d_in[4];
  const int*   rows   = (const int*)d_in[5];
  const int*   cols   = (const int*)d_in[6];
  const float* vals   = (const float*)d_in[7];
  float* out = (float*)d_out;

  const int N   = in_sizes[0] / FEAT;  // 100000
  const int nnz = in_sizes[5];         // 1600000

  // ws layout: cnt [N] i32 | rowsum [N] f32 | entries [N*CAP] int4 | agg [N,64] f32
  int*   cnt     = (int*)d_ws;
  float* rowsum  = (float*)(cnt + N);
  int4*  entries = (int4*)(rowsum + N);            // 800000 B offset: 16B-aligned
  float* agg     = (float*)(entries + (size_t)N * CAP);
  const size_t need = (size_t)N * 8 + (size_t)N * CAP * 16 + (size_t)N * FEAT * 4;

  if (ws_size >= need) {
    hipMemsetAsync(cnt, 0, (size_t)N * sizeof(int), stream);
    fill_entries_kernel<<<(nnz + 255) / 256, 256, 0, stream>>>(
        rows, cols, vals, X1, cnt, entries, nnz);
    gather_agg_kernel<<<(N + 3) / 4, 256, 0, stream>>>(
        nodes, cnt, entries, agg, rowsum, N);
    final_gemm_kernel<<<1563, 256, 0, stream>>>(agg, rowsum, W, bias, preluw,
                                                out, N);
  } else {
    float* agg2    = (float*)d_ws;
    float* rowsum2 = agg2 + (size_t)N * FEAT;
    hipMemsetAsync(d_ws, 0, ((size_t)N * FEAT + N) * sizeof(float), stream);
    scatter_xe_kernel<<<4096, 256, 0, stream>>>(nodes, X1, rows, cols, vals,
                                                agg2, rowsum2, nnz);
    final_gemm_kernel<<<1563, 256, 0, stream>>>(agg2, rowsum2, W, bias, preluw,
                                                out, N);
  }
}

// Round 6
// 201.606 us; speedup vs baseline: 1.3669x; 1.0925x over previous
//
#include <hip/hip_runtime.h>
#include <hip/hip_bf16.h>

// N_NODES=100000, N_EDGES=800000, FEAT=64, NNZ=1600000
// Inputs: 0 edge_list [N,64] f32 | 1 X1 [E,2] i32 | 2 W [64,64] f32 | 3 b [64] f32
//         4 prelu_w [1] f32 | 5 b1_rows [NNZ] i32 | 6 b1_cols [NNZ] i32 | 7 b1_vals [NNZ] f32
// Output: [N,64] f32
//
// out = PReLU( (B1 @ Xe) @ W^T + (B1 @ 1) b^T ),  Xe[c] = (n[u_c]-n[v_c])^2
//
// Round-6: (1) bf16 node table (halves gather bytes; 12.8 MB caches better),
// (2) agg stored bf16 (GEMM rounded to bf16 anyway -> no new error, -26 MB),
// (3) fill_entries x4-unrolled (int4 loads, 4 X1 gathers / atomics in flight).

#define FEAT 64
#define CAP  64   // Poisson(16) row degree; P(deg>64) ~ 1e-15 per row, guarded

typedef __attribute__((ext_vector_type(8))) short bf16x8;
typedef __attribute__((ext_vector_type(8))) unsigned short u16x8;
typedef __attribute__((ext_vector_type(4))) float f32x4;

__device__ inline short f2bf(float x) {
  union { __hip_bfloat16 h; short s; } u;
  u.h = __float2bfloat16(x);   // RNE
  return u.s;
}
__device__ inline float bf2f(unsigned short s) {
  return __uint_as_float((unsigned)s << 16);
}

// ---------------------------------------------------------------------------
// Kernel 0: f32 -> bf16 node table (one pass, 25.6 MB read / 12.8 MB write).
// ---------------------------------------------------------------------------
__global__ __launch_bounds__(256) void convert_nodes_kernel(
    const float* __restrict__ nodes,      // [N*64]
    unsigned short* __restrict__ nb,      // [N*64]
    int n8) {                             // (N*64)/8
  const int i = blockIdx.x * blockDim.x + threadIdx.x;
  if (i >= n8) return;
  const f32x4 a = *reinterpret_cast<const f32x4*>(&nodes[i * 8]);
  const f32x4 b = *reinterpret_cast<const f32x4*>(&nodes[i * 8 + 4]);
  u16x8 o;
#pragma unroll
  for (int e = 0; e < 4; ++e) {
    o[e]     = (unsigned short)f2bf(a[e]);
    o[4 + e] = (unsigned short)f2bf(b[e]);
  }
  *reinterpret_cast<u16x8*>(&nb[i * 8]) = o;
}

// ---------------------------------------------------------------------------
// Kernel 1: bucket nnz by row, resolving X1 once: entries[r*CAP+k]={u,w,val}.
// x4 unrolled: int4/float4 coalesced index loads, 4 independent X1 gathers,
// 4 independent atomics, 4 scatter stores.
// ---------------------------------------------------------------------------
__global__ __launch_bounds__(256) void fill_entries_kernel(
    const int*   __restrict__ rows,     // [NNZ]
    const int*   __restrict__ cols,     // [NNZ]
    const float* __restrict__ vals,     // [NNZ]
    const int*   __restrict__ X1,       // [E,2]
    int*         __restrict__ cnt,      // [N] pre-zeroed
    int4*        __restrict__ entries,  // [N*CAP]
    int nnz) {
  const int i = blockIdx.x * blockDim.x + threadIdx.x;
  const int nnz4 = nnz >> 2;
  const int2* X1v = reinterpret_cast<const int2*>(X1);

  if (i < nnz4) {
    const int4   r4 = reinterpret_cast<const int4*>(rows)[i];
    const int4   c4 = reinterpret_cast<const int4*>(cols)[i];
    const float4 v4 = reinterpret_cast<const float4*>(vals)[i];

    // 4 independent X1 gathers.
    const int2 uv0 = X1v[c4.x];
    const int2 uv1 = X1v[c4.y];
    const int2 uv2 = X1v[c4.z];
    const int2 uv3 = X1v[c4.w];

    // 4 independent bucket-slot atomics.
    const int k0 = atomicAdd(&cnt[r4.x], 1);
    const int k1 = atomicAdd(&cnt[r4.y], 1);
    const int k2 = atomicAdd(&cnt[r4.z], 1);
    const int k3 = atomicAdd(&cnt[r4.w], 1);

    if (k0 < CAP) entries[(size_t)r4.x * CAP + k0] = make_int4(uv0.x, uv0.y, __float_as_int(v4.x), 0);
    if (k1 < CAP) entries[(size_t)r4.y * CAP + k1] = make_int4(uv1.x, uv1.y, __float_as_int(v4.y), 0);
    if (k2 < CAP) entries[(size_t)r4.z * CAP + k2] = make_int4(uv2.x, uv2.y, __float_as_int(v4.z), 0);
    if (k3 < CAP) entries[(size_t)r4.w * CAP + k3] = make_int4(uv3.x, uv3.y, __float_as_int(v4.w), 0);
  } else if (i == nnz4) {
    // Tail (nnz % 4 != 0): scalar handling by one thread.
    for (int t = nnz4 * 4; t < nnz; ++t) {
      const int r = rows[t];
      const int2 uv = X1v[cols[t]];
      const int k = atomicAdd(&cnt[r], 1);
      if (k < CAP) entries[(size_t)r * CAP + k] = make_int4(uv.x, uv.y, __float_as_int(vals[t]), 0);
    }
  }
}

// ---------------------------------------------------------------------------
// Kernel 2: per-row gather-aggregate from the bf16 node table, 4x unrolled.
// One wave per row; lane j = feature j. agg stored as bf16.
// ---------------------------------------------------------------------------
__global__ __launch_bounds__(256) void gather_agg_kernel(
    const unsigned short* __restrict__ nb,   // [N,64] bf16
    const int*   __restrict__ cnt,           // [N]
    const int4*  __restrict__ entries,       // [N*CAP]
    unsigned short* __restrict__ aggb,       // [N,64] bf16
    float*       __restrict__ rowsum,        // [N]
    int N) {
  const int lane = threadIdx.x & 63;
  const int r = blockIdx.x * (blockDim.x >> 6) + (threadIdx.x >> 6);
  if (r >= N) return;

  int deg = cnt[r];
  if (deg > CAP) deg = CAP;
  const int4* base = &entries[(size_t)r * CAP];

  float acc = 0.f, rsum = 0.f;

  for (int k = 0; k < deg; k += 4) {
    // 4 wave-uniform entry loads (within CAP: groups 4-aligned, k+3 <= 63).
    const int4 e0 = base[k + 0];
    const int4 e1 = base[k + 1];
    const int4 e2 = base[k + 2];
    const int4 e3 = base[k + 3];

    // Mask the (at most one) partial tail group: index -> 0, weight -> 0.
    const bool m1 = (k + 1 < deg), m2 = (k + 2 < deg), m3 = (k + 3 < deg);
    const int   u0 = e0.x,            w0 = e0.y;
    const int   u1 = m1 ? e1.x : 0,   w1 = m1 ? e1.y : 0;
    const int   u2 = m2 ? e2.x : 0,   w2 = m2 ? e2.y : 0;
    const int   u3 = m3 ? e3.x : 0,   w3 = m3 ? e3.y : 0;
    const float v0 = __int_as_float(e0.z);
    const float v1 = m1 ? __int_as_float(e1.z) : 0.f;
    const float v2 = m2 ? __int_as_float(e2.z) : 0.f;
    const float v3 = m3 ? __int_as_float(e3.z) : 0.f;

    // 8 independent node-row gathers (128B coalesced each, bf16).
    const unsigned short a0 = nb[(size_t)u0 * FEAT + lane];
    const unsigned short b0 = nb[(size_t)w0 * FEAT + lane];
    const unsigned short a1 = nb[(size_t)u1 * FEAT + lane];
    const unsigned short b1 = nb[(size_t)w1 * FEAT + lane];
    const unsigned short a2 = nb[(size_t)u2 * FEAT + lane];
    const unsigned short b2 = nb[(size_t)w2 * FEAT + lane];
    const unsigned short a3 = nb[(size_t)u3 * FEAT + lane];
    const unsigned short b3 = nb[(size_t)w3 * FEAT + lane];

    rsum += (v0 + v1) + (v2 + v3);
    const float d0 = bf2f(a0) - bf2f(b0);
    const float d1 = bf2f(a1) - bf2f(b1);
    const float d2 = bf2f(a2) - bf2f(b2);
    const float d3 = bf2f(a3) - bf2f(b3);
    acc = fmaf(v0 * d0, d0, acc);
    acc = fmaf(v1 * d1, d1, acc);
    acc = fmaf(v2 * d2, d2, acc);
    acc = fmaf(v3 * d3, d3, acc);
  }

  aggb[(size_t)r * FEAT + lane] = (unsigned short)f2bf(acc);
  if (lane == 0) rowsum[r] = rsum;
}

// ---------------------------------------------------------------------------
// Kernel 3: out = PReLU( agg @ W^T + rowsum * b )  via mfma_f32_16x16x32_bf16.
// A-fragments load directly from bf16 agg (no conversion).
// Fragment layouts (gfx950, m89/m91-verified):
//   A[i][k]: i = lane&15, k = (lane>>4)*8 + e   (e = 0..7)
//   B[k][j]: j = lane&15, k = (lane>>4)*8 + e
//   D[i][j]: j = lane&15, i = (lane>>4)*4 + reg (reg = 0..3)
// ---------------------------------------------------------------------------
__global__ __launch_bounds__(256) void final_gemm_kernel(
    const unsigned short* __restrict__ aggb,  // [N,64] bf16
    const float* __restrict__ rowsum,         // [N]
    const float* __restrict__ W,              // [64,64]
    const float* __restrict__ bias,           // [64]
    const float* __restrict__ pw,             // [1]
    float*       __restrict__ out,            // [N,64]
    int nrows) {
  const int lane = threadIdx.x & 63;
  const int gw = blockIdx.x * (blockDim.x >> 6) + (threadIdx.x >> 6);
  const int nw = gridDim.x * (blockDim.x >> 6);

  const int lrow = lane & 15;
  const int kgrp = lane >> 4;
  const int k0   = kgrp * 8;

  bf16x8 bfrag[4][2];
#pragma unroll
  for (int jt = 0; jt < 4; ++jt) {
#pragma unroll
    for (int ks = 0; ks < 2; ++ks) {
      const float* wr = &W[(jt * 16 + lrow) * FEAT + ks * 32 + k0];
      bf16x8 t;
#pragma unroll
      for (int e = 0; e < 8; ++e) t[e] = f2bf(wr[e]);
      bfrag[jt][ks] = t;
    }
  }
  const float slope = pw[0];
  float bj[4];
#pragma unroll
  for (int jt = 0; jt < 4; ++jt) bj[jt] = bias[jt * 16 + lrow];

  const int ntiles = nrows >> 4;   // 100000 / 16 = 6250
  for (int t = gw; t < ntiles; t += nw) {
    const int rowbase = t * 16;

    bf16x8 afrag[2];
#pragma unroll
    for (int ks = 0; ks < 2; ++ks) {
      afrag[ks] = *reinterpret_cast<const bf16x8*>(
          &aggb[(size_t)(rowbase + lrow) * FEAT + ks * 32 + k0]);
    }

    float rs[4];
#pragma unroll
    for (int reg = 0; reg < 4; ++reg) rs[reg] = rowsum[rowbase + kgrp * 4 + reg];

#pragma unroll
    for (int jt = 0; jt < 4; ++jt) {
      f32x4 acc = {0.f, 0.f, 0.f, 0.f};
      acc = __builtin_amdgcn_mfma_f32_16x16x32_bf16(afrag[0], bfrag[jt][0], acc, 0, 0, 0);
      acc = __builtin_amdgcn_mfma_f32_16x16x32_bf16(afrag[1], bfrag[jt][1], acc, 0, 0, 0);
#pragma unroll
      for (int reg = 0; reg < 4; ++reg) {
        float y = acc[reg] + rs[reg] * bj[jt];
        y = y >= 0.f ? y : slope * y;
        out[(size_t)(rowbase + kgrp * 4 + reg) * FEAT + jt * 16 + lrow] = y;
      }
    }
  }
}

// ---------------------------------------------------------------------------
// Fallback (ws too small): atomic scatter path + f32 GEMM (round-2).
// ---------------------------------------------------------------------------
__global__ __launch_bounds__(256) void scatter_xe_kernel(
    const float* __restrict__ nodes,
    const int*   __restrict__ X1,
    const int*   __restrict__ rows,
    const int*   __restrict__ cols,
    const float* __restrict__ vals,
    float*       __restrict__ agg,
    float*       __restrict__ rowsum,
    int nnz) {
  const int lane = threadIdx.x & 63;
  const int gw = blockIdx.x * (blockDim.x >> 6) + (threadIdx.x >> 6);
  const int nw = gridDim.x * (blockDim.x >> 6);
  for (int i = gw; i < nnz; i += nw) {
    const int r = rows[i];
    const int c = cols[i];
    const float v = vals[i];
    const int u = X1[2 * c + 0];
    const int w = X1[2 * c + 1];
    const float a = nodes[(size_t)u * FEAT + lane];
    const float b = nodes[(size_t)w * FEAT + lane];
    const float d = a - b;
    atomicAdd(&agg[(size_t)r * FEAT + lane], v * d * d);
    if (lane == 0) atomicAdd(&rowsum[r], v);
  }
}

__global__ __launch_bounds__(256) void final_gemm_f32_kernel(
    const float* __restrict__ agg, const float* __restrict__ rowsum,
    const float* __restrict__ W, const float* __restrict__ bias,
    const float* __restrict__ pw, float* __restrict__ out, int nrows) {
  const int lane = threadIdx.x & 63;
  const int gw = blockIdx.x * (blockDim.x >> 6) + (threadIdx.x >> 6);
  const int nw = gridDim.x * (blockDim.x >> 6);
  const int lrow = lane & 15;
  const int kgrp = lane >> 4;
  const int k0   = kgrp * 8;

  bf16x8 bfrag[4][2];
#pragma unroll
  for (int jt = 0; jt < 4; ++jt)
#pragma unroll
    for (int ks = 0; ks < 2; ++ks) {
      const float* wr = &W[(jt * 16 + lrow) * FEAT + ks * 32 + k0];
      bf16x8 t;
#pragma unroll
      for (int e = 0; e < 8; ++e) t[e] = f2bf(wr[e]);
      bfrag[jt][ks] = t;
    }
  const float slope = pw[0];
  float bj[4];
#pragma unroll
  for (int jt = 0; jt < 4; ++jt) bj[jt] = bias[jt * 16 + lrow];

  const int ntiles = nrows >> 4;
  for (int t = gw; t < ntiles; t += nw) {
    const int rowbase = t * 16;
    bf16x8 afrag[2];
#pragma unroll
    for (int ks = 0; ks < 2; ++ks) {
      const float* ar = &agg[(size_t)(rowbase + lrow) * FEAT + ks * 32 + k0];
      f32x4 a0 = *reinterpret_cast<const f32x4*>(ar);
      f32x4 a1 = *reinterpret_cast<const f32x4*>(ar + 4);
      bf16x8 ta;
#pragma unroll
      for (int e = 0; e < 4; ++e) { ta[e] = f2bf(a0[e]); ta[4 + e] = f2bf(a1[e]); }
      afrag[ks] = ta;
    }
    float rs[4];
#pragma unroll
    for (int reg = 0; reg < 4; ++reg) rs[reg] = rowsum[rowbase + kgrp * 4 + reg];
#pragma unroll
    for (int jt = 0; jt < 4; ++jt) {
      f32x4 acc = {0.f, 0.f, 0.f, 0.f};
      acc = __builtin_amdgcn_mfma_f32_16x16x32_bf16(afrag[0], bfrag[jt][0], acc, 0, 0, 0);
      acc = __builtin_amdgcn_mfma_f32_16x16x32_bf16(afrag[1], bfrag[jt][1], acc, 0, 0, 0);
#pragma unroll
      for (int reg = 0; reg < 4; ++reg) {
        float y = acc[reg] + rs[reg] * bj[jt];
        y = y >= 0.f ? y : slope * y;
        out[(size_t)(rowbase + kgrp * 4 + reg) * FEAT + jt * 16 + lrow] = y;
      }
    }
  }
}

extern "C" void kernel_launch(void* const* d_in, const int* in_sizes, int n_in,
                              void* d_out, int out_size, void* d_ws, size_t ws_size,
                              hipStream_t stream) {
  const float* nodes  = (const float*)d_in[0];
  const int*   X1     = (const int*)d_in[1];
  const float* W      = (const float*)d_in[2];
  const float* bias   = (const float*)d_in[3];
  const float* preluw = (const float*)d_in[4];
  const int*   rows   = (const int*)d_in[5];
  const int*   cols   = (const int*)d_in[6];
  const float* vals   = (const float*)d_in[7];
  float* out = (float*)d_out;

  const int N   = in_sizes[0] / FEAT;  // 100000
  const int nnz = in_sizes[5];         // 1600000

  // ws layout: cnt [N] i32 | rowsum [N] f32 | entries [N*CAP] int4
  //            | nb [N*64] bf16 | aggb [N*64] bf16
  int*            cnt     = (int*)d_ws;
  float*          rowsum  = (float*)(cnt + N);
  int4*           entries = (int4*)(rowsum + N);           // 16B-aligned
  unsigned short* nb      = (unsigned short*)(entries + (size_t)N * CAP);
  unsigned short* aggb    = nb + (size_t)N * FEAT;
  const size_t need = (size_t)N * 8 + (size_t)N * CAP * 16 + (size_t)N * FEAT * 4;

  if (ws_size >= need) {
    hipMemsetAsync(cnt, 0, (size_t)N * sizeof(int), stream);
    const int n8 = N * FEAT / 8;
    convert_nodes_kernel<<<(n8 + 255) / 256, 256, 0, stream>>>(nodes, nb, n8);
    fill_entries_kernel<<<(nnz / 4 + 1 + 255) / 256, 256, 0, stream>>>(
        rows, cols, vals, X1, cnt, entries, nnz);
    gather_agg_kernel<<<(N + 3) / 4, 256, 0, stream>>>(
        nb, cnt, entries, aggb, rowsum, N);
    final_gemm_kernel<<<1563, 256, 0, stream>>>(aggb, rowsum, W, bias, preluw,
                                                out, N);
  } else {
    float* agg2    = (float*)d_ws;
    float* rowsum2 = agg2 + (size_t)N * FEAT;
    hipMemsetAsync(d_ws, 0, ((size_t)N * FEAT + N) * sizeof(float), stream);
    scatter_xe_kernel<<<4096, 256, 0, stream>>>(nodes, X1, rows, cols, vals,
                                                agg2, rowsum2, nnz);
    final_gemm_f32_kernel<<<1563, 256, 0, stream>>>(agg2, rowsum2, W, bias,
                                                    preluw, out, N);
  }
}